// Round 7
// baseline (231.012 us; speedup 1.0000x reference)
//
#include <hip/hip_runtime.h>

// ConvCaps2D with dynamic routing, fused single kernel. R7 = R6 with
// (a) __launch_bounds__(256,4): force total regs <= 128 (occupancy cliff
//     per m69: 4 waves/SIMD at <=128) instead of letting the allocator
//     park state in AGPRs at 2 waves/SIMD;
// (b) routing logits b kept ONLY in LDS (saves 9 persistent regs; each
//     thread touches only its own cell between barriers).
// B=8, 32x32x16 poses 4x4, 3x3 stride-2 VALID -> oh=ow=15, O=16, N=144.

#define OH 15
#define OW 15
#define N_VOTES 144
#define VPT 9            // votes per thread: 16*144/256
#define POSE_PAD 20      // LDS row stride for pose rows
#define B_PAD 17         // LDS row stride for b[n][o]

__device__ __forceinline__ unsigned int bf16rne(float f) {
    unsigned int x = __float_as_uint(f);
    return (x + 0x7fffu + ((x >> 16) & 1u)) >> 16;   // round-nearest-even
}
__device__ __forceinline__ float bf_lo(unsigned int pk) {
    return __uint_as_float(pk << 16);
}
__device__ __forceinline__ float bf_hi(unsigned int pk) {
    return __uint_as_float(pk & 0xffff0000u);
}

__global__ __launch_bounds__(256, 4)
void convcaps_routing_kernel(const float* __restrict__ poses,
                             const float* __restrict__ kern,
                             float* __restrict__ out)
{
    __shared__ float pose_lds[N_VOTES * POSE_PAD]; // 11520 B
    __shared__ float b_lds[N_VOTES * B_PAD];       // 9792 B
    __shared__ float nmax[N_VOTES];
    __shared__ float rden[N_VOTES];

    const int site = blockIdx.x;                   // 0..1799
    const int b    = site / (OH * OW);
    const int rem  = site % (OH * OW);
    const int h    = rem / OW;
    const int w    = rem % OW;

    const int t  = threadIdx.x;
    const int o  = t >> 4;                         // output channel 0..15
    const int nt = t & 15;                         // base vote index

    // ---- stage 144 pose matrices into LDS, float4 coalesced ----
    const float* pbase = poses + (size_t)b * (32 * 32 * 256);
    for (int idx = t; idx < N_VOTES * 4; idx += 256) {
        int n  = idx >> 2;
        int e4 = idx & 3;
        int kl = n >> 4;
        int c  = n & 15;
        int k  = kl / 3, l = kl % 3;
        int y  = 2 * h + k, x = 2 * w + l;
        const float4 v = *reinterpret_cast<const float4*>(
            pbase + (size_t)(y * 32 + x) * 256 + c * 16 + e4 * 4);
        *reinterpret_cast<float4*>(&pose_lds[n * POSE_PAD + e4 * 4]) = v;
    }
    __syncthreads();

    // ---- votes -> packed bf16 pairs in registers (plain C pack) ----
    unsigned int vp[VPT][8];
    #pragma unroll
    for (int j = 0; j < VPT; ++j) {
        const int n = nt + 16 * j;
        const float* Kp = kern + ((size_t)(o * N_VOTES + n) << 4);
        const float4 k0 = reinterpret_cast<const float4*>(Kp)[0];
        const float4 k1 = reinterpret_cast<const float4*>(Kp)[1];
        const float4 k2 = reinterpret_cast<const float4*>(Kp)[2];
        const float4 k3 = reinterpret_cast<const float4*>(Kp)[3];
        const float* P = &pose_lds[n * POSE_PAD];
        #pragma unroll
        for (int p = 0; p < 4; ++p) {
            const float p0 = P[p * 4 + 0], p1 = P[p * 4 + 1];
            const float p2 = P[p * 4 + 2], p3 = P[p * 4 + 3];
            const float e0 = p0 * k0.x + p1 * k1.x + p2 * k2.x + p3 * k3.x;
            const float e1 = p0 * k0.y + p1 * k1.y + p2 * k2.y + p3 * k3.y;
            const float e2 = p0 * k0.z + p1 * k1.z + p2 * k2.z + p3 * k3.z;
            const float e3 = p0 * k0.w + p1 * k1.w + p2 * k2.w + p3 * k3.w;
            vp[j][p * 2 + 0] = bf16rne(e0) | (bf16rne(e1) << 16);
            vp[j][p * 2 + 1] = bf16rne(e2) | (bf16rne(e3) << 16);
        }
    }

    float s[16];   // partial sum, then squashed v

    #pragma unroll
    for (int iter = 0; iter < 3; ++iter) {
        // s[o] = sum_n c * vote, c = softmax_o(b)
        #pragma unroll
        for (int e = 0; e < 16; ++e) s[e] = 0.0f;
        #pragma unroll
        for (int j = 0; j < VPT; ++j) {
            float c;
            if (iter == 0) c = 1.0f / 16.0f;
            else {
                const int n = nt + 16 * j;
                c = __expf(b_lds[n * B_PAD + o] - nmax[n]) * rden[n];
            }
            #pragma unroll
            for (int pr = 0; pr < 8; ++pr) {
                const unsigned int pk = vp[j][pr];
                s[2 * pr + 0] += c * bf_lo(pk);
                s[2 * pr + 1] += c * bf_hi(pk);
            }
        }
        // reduce across the 16 lanes of this o-group
        #pragma unroll
        for (int m = 1; m <= 8; m <<= 1) {
            #pragma unroll
            for (int e = 0; e < 16; ++e) s[e] += __shfl_xor(s[e], m, 64);
        }

        // squash
        float sq = 0.0f;
        #pragma unroll
        for (int e = 0; e < 16; ++e) sq += s[e] * s[e];
        const float factor = (sq / (1.0f + sq)) * rsqrtf(sq + 1e-9f);
        #pragma unroll
        for (int e = 0; e < 16; ++e) s[e] *= factor;

        if (iter < 2) {
            // b += dot(v, vote); b lives in LDS only (own cell, no race)
            #pragma unroll
            for (int j = 0; j < VPT; ++j) {
                float d = 0.0f;
                #pragma unroll
                for (int pr = 0; pr < 8; ++pr) {
                    const unsigned int pk = vp[j][pr];
                    d += s[2 * pr + 0] * bf_lo(pk);
                    d += s[2 * pr + 1] * bf_hi(pk);
                }
                const int idx = (nt + 16 * j) * B_PAD + o;
                const float bold = (iter == 0) ? 0.0f : b_lds[idx];
                b_lds[idx] = bold + d;
            }
            __syncthreads();
            if (t < N_VOTES) {
                float mx = -1e30f;
                #pragma unroll
                for (int oo = 0; oo < 16; ++oo)
                    mx = fmaxf(mx, b_lds[t * B_PAD + oo]);
                float sum = 0.0f;
                #pragma unroll
                for (int oo = 0; oo < 16; ++oo)
                    sum += __expf(b_lds[t * B_PAD + oo] - mx);
                nmax[t] = mx;
                rden[t] = 1.0f / sum;
            }
            __syncthreads();
        }
    }

    // ---- output ----
    // capsule_poses: [8,15,15,16,4,4] flat: site*256 + o*16 + e
    float vout = s[0];
    #pragma unroll
    for (int e = 1; e < 16; ++e) {
        if (nt == e) vout = s[e];
    }
    out[(size_t)site * 256 + t] = vout;

    // capsule_activations: [8,15,15,16] after poses (460800 floats)
    if (nt == 0) {
        float sqv = 0.0f;
        #pragma unroll
        for (int e = 0; e < 16; ++e) sqv += s[e] * s[e];
        out[460800 + (size_t)site * 16 + o] = sqrtf(sqv + 1e-12f);
    }
}

extern "C" void kernel_launch(void* const* d_in, const int* in_sizes, int n_in,
                              void* d_out, int out_size, void* d_ws, size_t ws_size,
                              hipStream_t stream) {
    const float* poses = (const float*)d_in[0];   // [8,32,32,16,4,4] f32
    // d_in[1] = input_activations: unused by the reference computation
    const float* kern  = (const float*)d_in[2];   // [16,3,3,16,4,4] f32
    float* outp = (float*)d_out;                  // 460800 poses + 28800 acts

    convcaps_routing_kernel<<<dim3(8 * OH * OW), dim3(256), 0, stream>>>(
        poses, kern, outp);
}

// Round 8
// 49.214 us; speedup vs baseline: 4.6940x; 4.6940x over previous
//
#include <hip/hip_runtime.h>

// ConvCaps2D with dynamic routing, fused single kernel. R8 = R6 +
// (a) routing logits b kept only in LDS (R7's change, -9 persistent regs;
//     correctness proven in R7),
// (b) __launch_bounds__(256,2) -- the only contract that never spilled,
// (c) sched_barrier(0) between the 9 vote-build iterations to cap peak
//     register pressure (stop cross-iteration interleave of K/P temps),
//     targeting total (VGPR+AGPR) <= 128 => 4 waves/SIMD naturally.
// B=8, 32x32x16 poses 4x4, 3x3 stride-2 VALID -> oh=ow=15, O=16, N=144.

#define OH 15
#define OW 15
#define N_VOTES 144
#define VPT 9            // votes per thread: 16*144/256
#define POSE_PAD 20      // LDS row stride for pose rows
#define B_PAD 17         // LDS row stride for b[n][o]

__device__ __forceinline__ unsigned int bf16rne(float f) {
    unsigned int x = __float_as_uint(f);
    return (x + 0x7fffu + ((x >> 16) & 1u)) >> 16;   // round-nearest-even
}
__device__ __forceinline__ float bf_lo(unsigned int pk) {
    return __uint_as_float(pk << 16);
}
__device__ __forceinline__ float bf_hi(unsigned int pk) {
    return __uint_as_float(pk & 0xffff0000u);
}

__global__ __launch_bounds__(256, 2)
void convcaps_routing_kernel(const float* __restrict__ poses,
                             const float* __restrict__ kern,
                             float* __restrict__ out)
{
    __shared__ float pose_lds[N_VOTES * POSE_PAD]; // 11520 B
    __shared__ float b_lds[N_VOTES * B_PAD];       // 9792 B
    __shared__ float nmax[N_VOTES];
    __shared__ float rden[N_VOTES];

    const int site = blockIdx.x;                   // 0..1799
    const int b    = site / (OH * OW);
    const int rem  = site % (OH * OW);
    const int h    = rem / OW;
    const int w    = rem % OW;

    const int t  = threadIdx.x;
    const int o  = t >> 4;                         // output channel 0..15
    const int nt = t & 15;                         // base vote index

    // ---- stage 144 pose matrices into LDS, float4 coalesced ----
    const float* pbase = poses + (size_t)b * (32 * 32 * 256);
    for (int idx = t; idx < N_VOTES * 4; idx += 256) {
        int n  = idx >> 2;
        int e4 = idx & 3;
        int kl = n >> 4;
        int c  = n & 15;
        int k  = kl / 3, l = kl % 3;
        int y  = 2 * h + k, x = 2 * w + l;
        const float4 v = *reinterpret_cast<const float4*>(
            pbase + (size_t)(y * 32 + x) * 256 + c * 16 + e4 * 4);
        *reinterpret_cast<float4*>(&pose_lds[n * POSE_PAD + e4 * 4]) = v;
    }
    __syncthreads();

    // ---- votes -> packed bf16 pairs in registers (plain C pack) ----
    // sched_barrier(0) between iterations: keep only ONE iteration's
    // K/P temps live at a time (peak-pressure cap, not a perf pin).
    unsigned int vp[VPT][8];
    #pragma unroll
    for (int j = 0; j < VPT; ++j) {
        const int n = nt + 16 * j;
        const float* Kp = kern + ((size_t)(o * N_VOTES + n) << 4);
        const float4 k0 = reinterpret_cast<const float4*>(Kp)[0];
        const float4 k1 = reinterpret_cast<const float4*>(Kp)[1];
        const float4 k2 = reinterpret_cast<const float4*>(Kp)[2];
        const float4 k3 = reinterpret_cast<const float4*>(Kp)[3];
        const float* P = &pose_lds[n * POSE_PAD];
        #pragma unroll
        for (int p = 0; p < 4; ++p) {
            const float p0 = P[p * 4 + 0], p1 = P[p * 4 + 1];
            const float p2 = P[p * 4 + 2], p3 = P[p * 4 + 3];
            const float e0 = p0 * k0.x + p1 * k1.x + p2 * k2.x + p3 * k3.x;
            const float e1 = p0 * k0.y + p1 * k1.y + p2 * k2.y + p3 * k3.y;
            const float e2 = p0 * k0.z + p1 * k1.z + p2 * k2.z + p3 * k3.z;
            const float e3 = p0 * k0.w + p1 * k1.w + p2 * k2.w + p3 * k3.w;
            vp[j][p * 2 + 0] = bf16rne(e0) | (bf16rne(e1) << 16);
            vp[j][p * 2 + 1] = bf16rne(e2) | (bf16rne(e3) << 16);
        }
        __builtin_amdgcn_sched_barrier(0);
    }

    float s[16];   // partial sum, then squashed v

    #pragma unroll
    for (int iter = 0; iter < 3; ++iter) {
        // s[o] = sum_n c * vote, c = softmax_o(b)
        #pragma unroll
        for (int e = 0; e < 16; ++e) s[e] = 0.0f;
        #pragma unroll
        for (int j = 0; j < VPT; ++j) {
            float c;
            if (iter == 0) c = 1.0f / 16.0f;
            else {
                const int n = nt + 16 * j;
                c = __expf(b_lds[n * B_PAD + o] - nmax[n]) * rden[n];
            }
            #pragma unroll
            for (int pr = 0; pr < 8; ++pr) {
                const unsigned int pk = vp[j][pr];
                s[2 * pr + 0] += c * bf_lo(pk);
                s[2 * pr + 1] += c * bf_hi(pk);
            }
        }
        // reduce across the 16 lanes of this o-group
        #pragma unroll
        for (int m = 1; m <= 8; m <<= 1) {
            #pragma unroll
            for (int e = 0; e < 16; ++e) s[e] += __shfl_xor(s[e], m, 64);
        }

        // squash
        float sq = 0.0f;
        #pragma unroll
        for (int e = 0; e < 16; ++e) sq += s[e] * s[e];
        const float factor = (sq / (1.0f + sq)) * rsqrtf(sq + 1e-9f);
        #pragma unroll
        for (int e = 0; e < 16; ++e) s[e] *= factor;

        if (iter < 2) {
            // b += dot(v, vote); b lives in LDS only (own cell, no race)
            #pragma unroll
            for (int j = 0; j < VPT; ++j) {
                float d = 0.0f;
                #pragma unroll
                for (int pr = 0; pr < 8; ++pr) {
                    const unsigned int pk = vp[j][pr];
                    d += s[2 * pr + 0] * bf_lo(pk);
                    d += s[2 * pr + 1] * bf_hi(pk);
                }
                const int idx = (nt + 16 * j) * B_PAD + o;
                const float bold = (iter == 0) ? 0.0f : b_lds[idx];
                b_lds[idx] = bold + d;
            }
            __syncthreads();
            if (t < N_VOTES) {
                float mx = -1e30f;
                #pragma unroll
                for (int oo = 0; oo < 16; ++oo)
                    mx = fmaxf(mx, b_lds[t * B_PAD + oo]);
                float sum = 0.0f;
                #pragma unroll
                for (int oo = 0; oo < 16; ++oo)
                    sum += __expf(b_lds[t * B_PAD + oo] - mx);
                nmax[t] = mx;
                rden[t] = 1.0f / sum;
            }
            __syncthreads();
        }
    }

    // ---- output ----
    // capsule_poses: [8,15,15,16,4,4] flat: site*256 + o*16 + e
    float vout = s[0];
    #pragma unroll
    for (int e = 1; e < 16; ++e) {
        if (nt == e) vout = s[e];
    }
    out[(size_t)site * 256 + t] = vout;

    // capsule_activations: [8,15,15,16] after poses (460800 floats)
    if (nt == 0) {
        float sqv = 0.0f;
        #pragma unroll
        for (int e = 0; e < 16; ++e) sqv += s[e] * s[e];
        out[460800 + (size_t)site * 16 + o] = sqrtf(sqv + 1e-12f);
    }
}

extern "C" void kernel_launch(void* const* d_in, const int* in_sizes, int n_in,
                              void* d_out, int out_size, void* d_ws, size_t ws_size,
                              hipStream_t stream) {
    const float* poses = (const float*)d_in[0];   // [8,32,32,16,4,4] f32
    // d_in[1] = input_activations: unused by the reference computation
    const float* kern  = (const float*)d_in[2];   // [16,3,3,16,4,4] f32
    float* outp = (float*)d_out;                  // 460800 poses + 28800 acts

    convcaps_routing_kernel<<<dim3(8 * OH * OW), dim3(256), 0, stream>>>(
        poses, kern, outp);
}